// Round 19
// baseline (179.208 us; speedup 1.0000x reference)
//
#include <hip/hip_runtime.h>

// EfficientAttention: N=8, C=256, H=W=128 (L=16384), HEADS=8, hc=32
// out = x + att,  att[n,h,cv,l] = sum_ck (ctx[ck,cv]/S[ck]) * softmax_ck(q)[ck,l]
// ctx[ck,cv] = sum_l exp(k[ck,l]) * v[cv,l],  S[ck] = sum_l exp(k[ck,l])
//
// R19 = R18 with W fragments loaded straight from global (L2) -> wlds removed,
// LDS 74 -> 50.4 KB -> 3 blocks/CU co-resident (12 waves, 3/SIMD). Grid 1024
// (1024 px/block, NT=16). Same fp8 staging GEMM, strips, counted vmcnt, k_att.

typedef __attribute__((ext_vector_type(8))) short short8;
typedef __attribute__((ext_vector_type(4))) float f32x4;
typedef long long ll;

#define NB     8
#define CCH    256
#define LSP    16384
#define NHEADS 8
#define HC     32
#define NT     16     // 64-px tiles per block (1024-px range)
#define WSC    0.015625f   // 1/64: undo W pre-scale

__device__ __forceinline__ unsigned short f2bf(float f) {
  union { float f; unsigned u; } v; v.f = f;
  unsigned r = v.u + 0x7fffu + ((v.u >> 16) & 1u);   // RNE
  return (unsigned short)(r >> 16);
}
__device__ __forceinline__ unsigned cvt_pk_bf16(float lo, float hi) {
  unsigned r;
  asm("v_cvt_pk_bf16_f32 %0, %1, %2" : "=v"(r) : "v"(lo), "v"(hi));
  return r;
}
// 4 floats -> 4 fp8 e4m3 packed in a u32 (HW cvt, RNE)
__device__ __forceinline__ unsigned cvt4_fp8(float a, float b, float c, float d) {
  unsigned r;
  asm("v_cvt_pk_fp8_f32 %0, %1, %2\n\t"
      "v_cvt_pk_fp8_f32 %0, %3, %4 op_sel:[0,0,1]"
      : "=v"(r) : "v"(a), "v"(b), "v"(c), "v"(d));
  return r;
}
// float -> fp8 e4m3fn (software, for once-only prep kernels)
__device__ __forceinline__ unsigned char f2fp8(float f) {
  union { float f; unsigned u; } v; v.f = f;
  unsigned s = (v.u >> 24) & 0x80u;
  unsigned x = v.u & 0x7FFFFFFFu;
  if (x < 0x3C800000u) {
    float a = fabsf(f);
    int q = (int)rintf(a * 512.f);
    return (unsigned char)(s | (unsigned)q);
  }
  unsigned r = x + 0xFFFFFu + ((x >> 20) & 1u);
  unsigned e = r >> 23;
  unsigned m = (r >> 20) & 7u;
  int fe = (int)e - 120;
  if (fe > 15 || (fe == 15 && m == 7)) return (unsigned char)(s | 0x7Eu);
  return (unsigned char)(s | ((unsigned)fe << 3) | m);
}
__device__ __forceinline__ void gload_lds16(const unsigned char* g, unsigned char* l) {
  __builtin_amdgcn_global_load_lds(
      (const __attribute__((address_space(1))) unsigned int*)g,
      (__attribute__((address_space(3))) unsigned int*)l, 16, 0, 0);
}

// ---------------- kernel 0: weights -> fp8 (x64 pre-scale) head-grouped [k32|v32|q32] ------
__global__ void k_prep(const float* __restrict__ Wk, const float* __restrict__ bk,
                       const float* __restrict__ Wq, const float* __restrict__ bq,
                       const float* __restrict__ Wv, const float* __restrict__ bv,
                       unsigned char* __restrict__ Wb, float* __restrict__ bb,
                       float* __restrict__ ctx, float* __restrict__ S) {
  int idx = blockIdx.x * 256 + threadIdx.x;
  if (idx < NHEADS * 96 * CCH) {
    int c = idx & (CCH - 1);
    int row = (idx >> 8) % 96;
    int h = idx / (96 * CCH);
    int ch = h * HC;
    float val;
    if (row < HC)          val = Wk[(ch + row) * CCH + c];
    else if (row < 2 * HC) val = Wv[(ch + row - HC) * CCH + c];
    else                   val = Wq[(ch + row - 2 * HC) * CCH + c];
    Wb[idx] = f2fp8(val * 64.f);
  }
  if (idx < NHEADS * 96) {
    int row = idx % 96, h = idx / 96, ch = h * HC;
    float val;
    if (row < HC)          val = bk[ch + row];
    else if (row < 2 * HC) val = bv[ch + row - HC];
    else                   val = bq[ch + row - 2 * HC];
    bb[idx] = val;
  }
  if (idx < NB * NHEADS * HC * HC) ctx[idx] = 0.f;
  if (idx < NB * NHEADS * HC)      S[idx]   = 0.f;
}

// ---------------- kernel 0b: x [n][c][l] f32 -> xT [n][l][c] fp8 ----------------
__global__ __launch_bounds__(256)
void k_transpose(const float* __restrict__ x, unsigned char* __restrict__ xT) {
  __shared__ float tile[64][65];
  int b = blockIdx.x;
  int ct = b & 3;
  int lt = (b >> 2) & 255;
  int n  = b >> 10;
  int c0 = ct * 64, l0 = lt * 64;
  int t = threadIdx.x;
  int li = t & 63, cr = t >> 6;
  const float* xp = x + (size_t)n * CCH * LSP;
#pragma unroll
  for (int i = 0; i < 16; ++i) {
    int ci = cr * 16 + i;
    tile[ci][li] = xp[(size_t)(c0 + ci) * LSP + l0 + li];
  }
  __syncthreads();
  int cq = t & 15, lg = t >> 4;
  unsigned char* xo = xT + ((size_t)n * LSP + l0) * CCH + c0;
#pragma unroll
  for (int i = 0; i < 4; ++i) {
    int l = lg * 4 + i;
    unsigned pk = cvt4_fp8(tile[cq * 4][l], tile[cq * 4 + 1][l],
                           tile[cq * 4 + 2][l], tile[cq * 4 + 3][l]);
    *(unsigned*)&xo[(size_t)l * CCH + cq * 4] = pk;
  }
}

// ---------------- kernel 1: fused QKV, 3 blocks/CU, W frags from global ----------------
// grid 1024 = 8h x 8n x 16g; bid = h*128 + n*16 + g -> h-siblings differ by 128
// (mult of 8) -> same XCD (x L2-shared). 4 waves = rh{0,1} x pq{0,1};
// wave tile 48 rows x 32 px, fp8 frags. W frags (24 b64 = 48 VGPR) loaded once
// from global (L2-resident). LDS 50.4 KB -> 3 blocks/CU. Counted vmcnt as R18.
__global__ __launch_bounds__(256)
void k_fused(const unsigned char* __restrict__ xT,
             const unsigned char* __restrict__ Wb, const float* __restrict__ bb,
             unsigned char* __restrict__ qbuf, float* __restrict__ ctx,
             float* __restrict__ S) {
  __shared__ unsigned char xt[2][64 * 256];       // 32 KiB dbuf
  __shared__ unsigned short ekst[2][32][72];      // 9 KiB exp(k) strips, dbuf
  __shared__ unsigned short vst[2][32][72];       // 9 KiB v strips, dbuf

  int bid = (int)blockIdx.x;
  int h = bid >> 7;
  int r7 = bid & 127;
  int n = r7 >> 4, g = r7 & 15;
  int l0 = g << 10;                  // 1024-px range
  int nh = n * NHEADS + h;
  int tid = threadIdx.x;
  int wid = tid >> 6, lane = tid & 63;
  int r16 = lane & 15, kg = lane >> 4;
  int rh = wid >> 1;          // row half (48 rows)
  int pq = wid & 1;           // px half (32 px)

  const unsigned char* xTn = xT + ((size_t)n << 14) * CCH;
  const unsigned char* Wh = Wb + (size_t)h * 96 * CCH;

  // ---- W fragments -> registers, once, straight from global (L2) ----
  ll wf[3][8];
#pragma unroll
  for (int m = 0; m < 3; ++m)
#pragma unroll
    for (int kk = 0; kk < 8; ++kk)
      wf[m][kk] = *(const ll*)&Wh[(size_t)(rh * 48 + m * 16 + r16) * CCH + kk * 32 + kg * 8];

  // stage 64px x 256ch fp8 tile: 16 x 1KiB pieces, 4/wave; dest linear,
  // source 16B-chunk XOR (3-bit involution, rule 21)
  auto stage_xt = [&](int buf, int tt) {
    int lb = l0 + tt * 64;
#pragma unroll
    for (int i = 0; i < 4; ++i) {
      int p = wid * 4 + i;                   // 0..15
      int px = p * 4 + (lane >> 4);
      int c16 = lane & 15;
      gload_lds16(xTn + ((size_t)(lb + px) << 8) + ((c16 ^ (px & 7)) << 4),
                  &xt[buf][p * 1024]);
    }
  };

  stage_xt(0, 0);
  stage_xt(1, 1);

  float bw[3];
#pragma unroll
  for (int m = 0; m < 3; ++m) bw[m] = bb[h * 96 + rh * 48 + m * 16 + r16];
  float bq[2][4];
#pragma unroll
  for (int m = 0; m < 2; ++m)
#pragma unroll
    for (int r = 0; r < 4; ++r) bq[m][r] = bb[h * 96 + 64 + m * 16 + kg * 4 + r];

  f32x4 actx = {0.f, 0.f, 0.f, 0.f};   // quadrant (ckf=rh, cvf=pq), K = full 64 px
  float sk0 = 0.f, sk1 = 0.f;

  // drain W loads + tile0 DMA; tile1 stays in flight (4/wave)
  asm volatile("s_waitcnt vmcnt(4)" ::: "memory");
  __builtin_amdgcn_sched_barrier(0);
  __builtin_amdgcn_s_barrier();
  __builtin_amdgcn_sched_barrier(0);

  const int base_x = (pq * 32 + r16) * 256;

  for (int t = 0; t < NT; ++t) {
    int cur = t & 1, sb = t & 1, pb = sb ^ 1;
    // ---- ctx MFMA on previous tile's strips (bf16, one tile behind) ----
    if (t) {
#pragma unroll
      for (int ks = 0; ks < 2; ++ks) {
        int col = ks * 32 + kg * 8;
        short8 a = *(const short8*)&ekst[pb][rh * 16 + r16][col];
        short8 b = *(const short8*)&vst[pb][pq * 16 + r16][col];
        actx = __builtin_amdgcn_mfma_f32_16x16x32_bf16(a, b, actx, 0, 0, 0);
      }
    }
    // ---- K-loop: 48 rows x 32 px; only 2 x-frag b64 reads per kk ----
    f32x4 acc[3][2];
#pragma unroll
    for (int m = 0; m < 3; ++m) { acc[m][0] = (f32x4){0,0,0,0}; acc[m][1] = (f32x4){0,0,0,0}; }
    const unsigned char* xb = &xt[cur][0];
#pragma unroll
    for (int kk = 0; kk < 8; ++kk) {
      int sw = (((kk * 2 + (kg >> 1)) ^ (r16 & 7)) << 4) + ((kg & 1) << 3);
      ll xf0 = *(const ll*)&xb[base_x + sw];
      ll xf1 = *(const ll*)&xb[base_x + 4096 + sw];
      if (rh == 0) {
        acc[0][0] = __builtin_amdgcn_mfma_f32_16x16x32_fp8_fp8(xf0, wf[0][kk], acc[0][0], 0, 0, 0);
        acc[0][1] = __builtin_amdgcn_mfma_f32_16x16x32_fp8_fp8(xf1, wf[0][kk], acc[0][1], 0, 0, 0);
        acc[1][0] = __builtin_amdgcn_mfma_f32_16x16x32_fp8_fp8(xf0, wf[1][kk], acc[1][0], 0, 0, 0);
        acc[1][1] = __builtin_amdgcn_mfma_f32_16x16x32_fp8_fp8(xf1, wf[1][kk], acc[1][1], 0, 0, 0);
        acc[2][0] = __builtin_amdgcn_mfma_f32_16x16x32_fp8_fp8(xf0, wf[2][kk], acc[2][0], 0, 0, 0);
        acc[2][1] = __builtin_amdgcn_mfma_f32_16x16x32_fp8_fp8(xf1, wf[2][kk], acc[2][1], 0, 0, 0);
      } else {
        acc[0][0] = __builtin_amdgcn_mfma_f32_16x16x32_fp8_fp8(xf0, wf[0][kk], acc[0][0], 0, 0, 0);
        acc[0][1] = __builtin_amdgcn_mfma_f32_16x16x32_fp8_fp8(xf1, wf[0][kk], acc[0][1], 0, 0, 0);
        acc[1][0] = __builtin_amdgcn_mfma_f32_16x16x32_fp8_fp8(wf[1][kk], xf0, acc[1][0], 0, 0, 0);
        acc[1][1] = __builtin_amdgcn_mfma_f32_16x16x32_fp8_fp8(wf[1][kk], xf1, acc[1][1], 0, 0, 0);
        acc[2][0] = __builtin_amdgcn_mfma_f32_16x16x32_fp8_fp8(wf[2][kk], xf0, acc[2][0], 0, 0, 0);
        acc[2][1] = __builtin_amdgcn_mfma_f32_16x16x32_fp8_fp8(wf[2][kk], xf1, acc[2][1], 0, 0, 0);
      }
    }
    __builtin_amdgcn_s_barrier();          // barrier1: all waves done reading xt[cur]
    if (t + 2 < NT) stage_xt(cur, t + 2);  // refill freed buffer; full-tile DMA window

    // ---- epilogue (wave-local); acc * 1/64 undoes W pre-scale ----
    if (rh == 0) {
#pragma unroll
      for (int nf = 0; nf < 2; ++nf) {
        int col = pq * 32 + nf * 16 + kg * 4;
#pragma unroll
        for (int m = 0; m < 2; ++m) {       // k rows -> exp strips + S
          float e0 = __expf(acc[m][nf][0] * WSC + bw[m]);
          float e1 = __expf(acc[m][nf][1] * WSC + bw[m]);
          float e2 = __expf(acc[m][nf][2] * WSC + bw[m]);
          float e3 = __expf(acc[m][nf][3] * WSC + bw[m]);
          if (m == 0) sk0 += e0 + e1 + e2 + e3; else sk1 += e0 + e1 + e2 + e3;
          uint2 u = {cvt_pk_bf16(e0, e1), cvt_pk_bf16(e2, e3)};
          *(uint2*)&ekst[sb][m * 16 + r16][col] = u;
        }
        {                                    // v rows 0-15
          float v0 = acc[2][nf][0] * WSC + bw[2], v1 = acc[2][nf][1] * WSC + bw[2];
          float v2 = acc[2][nf][2] * WSC + bw[2], v3 = acc[2][nf][3] * WSC + bw[2];
          uint2 u = {cvt_pk_bf16(v0, v1), cvt_pk_bf16(v2, v3)};
          *(uint2*)&vst[sb][r16][col] = u;
        }
      }
    } else {
#pragma unroll
      for (int nf = 0; nf < 2; ++nf) {
        int col = pq * 32 + nf * 16 + kg * 4;
        {                                    // v rows 16-31
          float v0 = acc[0][nf][0] * WSC + bw[0], v1 = acc[0][nf][1] * WSC + bw[0];
          float v2 = acc[0][nf][2] * WSC + bw[0], v3 = acc[0][nf][3] * WSC + bw[0];
          uint2 u = {cvt_pk_bf16(v0, v1), cvt_pk_bf16(v2, v3)};
          *(uint2*)&vst[sb][16 + r16][col] = u;
        }
        // q: softmax over 32 ck, wholly in-wave (8 in-lane + shfl 16,32); store fp8
        float ea[4], eb[4];
        float s = 0.f;
#pragma unroll
        for (int r = 0; r < 4; ++r) {
          ea[r] = __expf(acc[1][nf][r] * WSC + bq[0][r]);
          eb[r] = __expf(acc[2][nf][r] * WSC + bq[1][r]);
          s += ea[r] + eb[r];
        }
        s += __shfl_xor(s, 16);
        s += __shfl_xor(s, 32);
        float inv = 1.f / s;
        int l = l0 + t * 64 + pq * 32 + nf * 16 + r16;
        unsigned char* qb = qbuf + (((size_t)nh * LSP + l) << 5);
        unsigned u0 = cvt4_fp8(ea[0] * inv, ea[1] * inv, ea[2] * inv, ea[3] * inv);
        unsigned u1 = cvt4_fp8(eb[0] * inv, eb[1] * inv, eb[2] * inv, eb[3] * inv);
        *(unsigned*)&qb[kg * 4]      = u0;
        *(unsigned*)&qb[16 + kg * 4] = u1;
      }
    }
    // barrier2: strips visible; next tile's buffer staged (counted, per-role)
    asm volatile("s_waitcnt lgkmcnt(0)" ::: "memory");
    __builtin_amdgcn_sched_barrier(0);
    if (t < NT - 2) {
      if (rh == 0) { asm volatile("s_waitcnt vmcnt(4)" ::: "memory"); }
      else         { asm volatile("s_waitcnt vmcnt(8)" ::: "memory"); }
    } else if (t == NT - 2) {
      if (rh == 0) { asm volatile("s_waitcnt vmcnt(0)" ::: "memory"); }
      else         { asm volatile("s_waitcnt vmcnt(4)" ::: "memory"); }
    }
    __builtin_amdgcn_sched_barrier(0);
    __builtin_amdgcn_s_barrier();
    __builtin_amdgcn_sched_barrier(0);
  }

  // final ctx on last tile's strips
#pragma unroll
  for (int ks = 0; ks < 2; ++ks) {
    int col = ks * 32 + kg * 8;
    short8 a = *(const short8*)&ekst[(NT - 1) & 1][rh * 16 + r16][col];
    short8 b = *(const short8*)&vst[(NT - 1) & 1][pq * 16 + r16][col];
    actx = __builtin_amdgcn_mfma_f32_16x16x32_bf16(a, b, actx, 0, 0, 0);
  }
  // flush: ctx quadrant + S rows
  float* cp = ctx + ((size_t)nh << 10);
#pragma unroll
  for (int r = 0; r < 4; ++r)
    atomicAdd(&cp[(rh * 16 + kg * 4 + r) * HC + pq * 16 + r16], actx[r]);
  if (rh == 0) {
    float s0 = sk0, s1 = sk1;
    s0 += __shfl_xor(s0, 16); s0 += __shfl_xor(s0, 32);
    s1 += __shfl_xor(s1, 16); s1 += __shfl_xor(s1, 32);
    if (kg == 0) {
      atomicAdd(&S[nh * HC + r16], s0);
      atomicAdd(&S[nh * HC + 16 + r16], s1);
    }
  }
}

// ---------------- kernel 2: ctx/S, transpose, -> fp8 ----------------
__global__ void k_norm(const float* __restrict__ ctx, const float* __restrict__ S,
                       unsigned char* __restrict__ ctxT) {
  int idx = blockIdx.x * 256 + threadIdx.x;  // 65536 = [n][h][ck][cv]
  int cv = idx & 31, ck = (idx >> 5) & 31, nh = idx >> 10;
  float v = ctx[idx] / S[(nh << 5) + ck];
  ctxT[(nh << 10) + (cv << 5) + ck] = f2fp8(v);
}

// ---------------- kernel 3: att = ctxT (fp8) x q_soft (fp8) + residual ----------------
__global__ __launch_bounds__(256)
void k_att(const float* __restrict__ x, const unsigned char* __restrict__ qbuf,
           const unsigned char* __restrict__ ctxT, float* __restrict__ out) {
  int b = blockIdx.x;
  int lc = b & 63;
  int nh = b >> 6;
  int h = nh & 7, n = nh >> 3;
  int tid = threadIdx.x, wid = tid >> 6, lane = tid & 63;
  int r16 = lane & 15, kg = lane >> 4;
  int lw = lc * 256 + wid * 64;

  const unsigned char* cp = ctxT + ((size_t)nh << 10);
  ll a0 = *(const ll*)&cp[(r16 << 5) + kg * 8];          // A[cv][ck], cv 0-15
  ll a1 = *(const ll*)&cp[((16 + r16) << 5) + kg * 8];   // cv 16-31
  const unsigned char* qb = qbuf + (((size_t)nh * LSP) << 5);
  const float* xp = x   + ((size_t)n * CCH + (size_t)h * HC) * LSP;
  float*       op = out + ((size_t)n * CCH + (size_t)h * HC) * LSP;

#pragma unroll
  for (int t = 0; t < 4; ++t) {
    int l = lw + t * 16;
    ll bq = *(const ll*)&qb[((size_t)(l + r16) << 5) + kg * 8];  // softmaxed q [l][ck] fp8
    f32x4 d0 = {0, 0, 0, 0}, d1 = {0, 0, 0, 0};
    d0 = __builtin_amdgcn_mfma_f32_16x16x32_fp8_fp8(a0, bq, d0, 0, 0, 0);
    d1 = __builtin_amdgcn_mfma_f32_16x16x32_fp8_fp8(a1, bq, d1, 0, 0, 0);
#pragma unroll
    for (int r = 0; r < 4; ++r) {
      int cv = kg * 4 + r;
      int li = l + r16;
      op[(size_t)cv * LSP + li]        = d0[r] + xp[(size_t)cv * LSP + li];
      op[(size_t)(cv + 16) * LSP + li] = d1[r] + xp[(size_t)(cv + 16) * LSP + li];
    }
  }
}

extern "C" void kernel_launch(void* const* d_in, const int* in_sizes, int n_in,
                              void* d_out, int out_size, void* d_ws, size_t ws_size,
                              hipStream_t stream) {
  (void)in_sizes; (void)n_in; (void)out_size; (void)ws_size;
  const float* x  = (const float*)d_in[0];
  const float* Wk = (const float*)d_in[1];
  const float* bk = (const float*)d_in[2];
  const float* Wq = (const float*)d_in[3];
  const float* bq = (const float*)d_in[4];
  const float* Wv = (const float*)d_in[5];
  const float* bv = (const float*)d_in[6];
  float* out = (float*)d_out;

  char* ws = (char*)d_ws;
  unsigned char*  Wb   = (unsigned char*)(ws + 0);           //    196608 (fp8, x64-scaled)
  float*          bbp  = (float*)(ws + 196608);              //      3072
  float*          ctx  = (float*)(ws + 199680);              //    262144
  unsigned char*  ctxT = (unsigned char*)(ws + 461824);      //     32768 (fp8)
  float*          S    = (float*)(ws + 494592);              //      8192
  unsigned char*  qbuf = (unsigned char*)(ws + 502784);      //  33554432 (fp8)
  unsigned char*  xT   = (unsigned char*)(ws + 34057216);    //  33554432 (fp8) -> 67611648

  k_prep<<<768, 256, 0, stream>>>(Wk, bk, Wq, bq, Wv, bv, Wb, bbp, ctx, S);
  k_transpose<<<NB * 256 * 4, 256, 0, stream>>>(x, xT);
  k_fused<<<1024, 256, 0, stream>>>(xT, Wb, bbp, qbuf, ctx, S);
  k_norm<<<256, 256, 0, stream>>>(ctx, S, ctxT);
  k_att<<<NB * NHEADS * 64, 256, 0, stream>>>(x, qbuf, ctxT, out);
}

// Round 20
// 177.534 us; speedup vs baseline: 1.0094x; 1.0094x over previous
//
#include <hip/hip_runtime.h>

// EfficientAttention: N=8, C=256, H=W=128 (L=16384), HEADS=8, hc=32
// out = x + att,  att[n,h,cv,l] = sum_ck (ctx[ck,cv]/S[ck]) * softmax_ck(q)[ck,l]
// ctx[ck,cv] = sum_l exp(k[ck,l]) * v[cv,l],  S[ck] = sum_l exp(k[ck,l])
//
// R20 = R18 k_fused verbatim (best measured: 2 blocks/CU, W frags in regs,
// fp8 staging, counted vmcnt) + prep merged into transpose launch (hides ~4us)
// + k_norm folded into k_att (ctx/S read directly, fp8 A-frags built in-reg).
// R19's 3-blocks/CU regressed (tail round + W refetch) -> reverted.

typedef __attribute__((ext_vector_type(8))) short short8;
typedef __attribute__((ext_vector_type(4))) float f32x4;
typedef long long ll;

#define NB     8
#define CCH    256
#define LSP    16384
#define NHEADS 8
#define HC     32
#define NT     32     // 64-px tiles per block (2048-px range)
#define WSC    0.015625f   // 1/64: undo W pre-scale

__device__ __forceinline__ unsigned cvt_pk_bf16(float lo, float hi) {
  unsigned r;
  asm("v_cvt_pk_bf16_f32 %0, %1, %2" : "=v"(r) : "v"(lo), "v"(hi));
  return r;
}
// 4 floats -> 4 fp8 e4m3 packed in a u32 (HW cvt, RNE)
__device__ __forceinline__ unsigned cvt4_fp8(float a, float b, float c, float d) {
  unsigned r;
  asm("v_cvt_pk_fp8_f32 %0, %1, %2\n\t"
      "v_cvt_pk_fp8_f32 %0, %3, %4 op_sel:[0,0,1]"
      : "=v"(r) : "v"(a), "v"(b), "v"(c), "v"(d));
  return r;
}
// float -> fp8 e4m3fn (software, for once-only prep path)
__device__ __forceinline__ unsigned char f2fp8(float f) {
  union { float f; unsigned u; } v; v.f = f;
  unsigned s = (v.u >> 24) & 0x80u;
  unsigned x = v.u & 0x7FFFFFFFu;
  if (x < 0x3C800000u) {
    float a = fabsf(f);
    int q = (int)rintf(a * 512.f);
    return (unsigned char)(s | (unsigned)q);
  }
  unsigned r = x + 0xFFFFFu + ((x >> 20) & 1u);
  unsigned e = r >> 23;
  unsigned m = (r >> 20) & 7u;
  int fe = (int)e - 120;
  if (fe > 15 || (fe == 15 && m == 7)) return (unsigned char)(s | 0x7Eu);
  return (unsigned char)(s | ((unsigned)fe << 3) | m);
}
__device__ __forceinline__ void gload_lds16(const unsigned char* g, unsigned char* l) {
  __builtin_amdgcn_global_load_lds(
      (const __attribute__((address_space(1))) unsigned int*)g,
      (__attribute__((address_space(3))) unsigned int*)l, 16, 0, 0);
}

// ---------------- kernel 0: transpose (blocks 0..8191) + prep (blocks 8192..8959) --------
// transpose: x [n][c][l] f32 -> xT [n][l][c] fp8.
// prep: weights -> fp8 (x64 pre-scale) head-grouped [k32|v32|q32]; biases; zero ctx/S.
__global__ __launch_bounds__(256)
void k_pre(const float* __restrict__ x, unsigned char* __restrict__ xT,
           const float* __restrict__ Wk, const float* __restrict__ bk,
           const float* __restrict__ Wq, const float* __restrict__ bq,
           const float* __restrict__ Wv, const float* __restrict__ bv,
           unsigned char* __restrict__ Wb, float* __restrict__ bb,
           float* __restrict__ ctx, float* __restrict__ S) {
  __shared__ float tile[64][65];
  int b = blockIdx.x;
  if (b < 8192) {
    int ct = b & 3;
    int lt = (b >> 2) & 255;
    int n  = b >> 10;
    int c0 = ct * 64, l0 = lt * 64;
    int t = threadIdx.x;
    int li = t & 63, cr = t >> 6;
    const float* xp = x + (size_t)n * CCH * LSP;
#pragma unroll
    for (int i = 0; i < 16; ++i) {
      int ci = cr * 16 + i;
      tile[ci][li] = xp[(size_t)(c0 + ci) * LSP + l0 + li];
    }
    __syncthreads();
    int cq = t & 15, lg = t >> 4;
    unsigned char* xo = xT + ((size_t)n * LSP + l0) * CCH + c0;
#pragma unroll
    for (int i = 0; i < 4; ++i) {
      int l = lg * 4 + i;
      unsigned pk = cvt4_fp8(tile[cq * 4][l], tile[cq * 4 + 1][l],
                             tile[cq * 4 + 2][l], tile[cq * 4 + 3][l]);
      *(unsigned*)&xo[(size_t)l * CCH + cq * 4] = pk;
    }
  } else {
    int idx = (b - 8192) * 256 + threadIdx.x;
    if (idx < NHEADS * 96 * CCH) {
      int c = idx & (CCH - 1);
      int row = (idx >> 8) % 96;
      int h = idx / (96 * CCH);
      int ch = h * HC;
      float val;
      if (row < HC)          val = Wk[(ch + row) * CCH + c];
      else if (row < 2 * HC) val = Wv[(ch + row - HC) * CCH + c];
      else                   val = Wq[(ch + row - 2 * HC) * CCH + c];
      Wb[idx] = f2fp8(val * 64.f);
    }
    if (idx < NHEADS * 96) {
      int row = idx % 96, h = idx / 96, ch = h * HC;
      float val;
      if (row < HC)          val = bk[ch + row];
      else if (row < 2 * HC) val = bv[ch + row - HC];
      else                   val = bq[ch + row - 2 * HC];
      bb[idx] = val;
    }
    if (idx < NB * NHEADS * HC * HC) ctx[idx] = 0.f;
    if (idx < NB * NHEADS * HC)      S[idx]   = 0.f;
  }
}

// ---------------- kernel 1: fused QKV, 2 blocks/CU, W frags in registers (R18) ------------
// grid 512 = 8h x 8n x 8g; bid = h*64 + n*8 + g -> h-siblings differ by 64 (mult of 8)
// -> same XCD (x L2-shared). 4 waves = rh{0,1} x pq{0,1}; wave tile 48 rows x 32 px.
// W frags loaded to regs once from LDS (24 b64 = 48 VGPR) -> K-loop reads 2 x-frags/kk.
__global__ __launch_bounds__(256)
void k_fused(const unsigned char* __restrict__ xT,
             const unsigned char* __restrict__ Wb, const float* __restrict__ bb,
             unsigned char* __restrict__ qbuf, float* __restrict__ ctx,
             float* __restrict__ S) {
  __shared__ unsigned char wlds[96 * 256];        // 24 KiB (staged once)
  __shared__ unsigned char xt[2][64 * 256];       // 32 KiB dbuf
  __shared__ unsigned short ekst[2][32][72];      // 9 KiB exp(k) strips, dbuf
  __shared__ unsigned short vst[2][32][72];       // 9 KiB v strips, dbuf

  int bid = (int)blockIdx.x;
  int h = bid >> 6;
  int r6 = bid & 63;
  int n = r6 >> 3, g = r6 & 7;
  int l0 = g << 11;                  // 2048-px range
  int nh = n * NHEADS + h;
  int tid = threadIdx.x;
  int wid = tid >> 6, lane = tid & 63;
  int r16 = lane & 15, kg = lane >> 4;
  int rh = wid >> 1;          // row half (48 rows)
  int pq = wid & 1;           // px half (32 px)

  const unsigned char* xTn = xT + ((size_t)n << 14) * CCH;
  const unsigned char* Wh = Wb + (size_t)h * 96 * CCH;

  // stage 64px x 256ch fp8 tile: 16 x 1KiB pieces, 4/wave; dest linear,
  // source 16B-chunk XOR (3-bit involution, rule 21)
  auto stage_xt = [&](int buf, int tt) {
    int lb = l0 + tt * 64;
#pragma unroll
    for (int i = 0; i < 4; ++i) {
      int p = wid * 4 + i;                   // 0..15
      int px = p * 4 + (lane >> 4);
      int c16 = lane & 15;
      gload_lds16(xTn + ((size_t)(lb + px) << 8) + ((c16 ^ (px & 7)) << 4),
                  &xt[buf][p * 1024]);
    }
  };

  // prologue: W (24 pieces, 6/wave) + tiles 0,1
#pragma unroll
  for (int i = 0; i < 6; ++i) {
    int p = wid * 6 + i;
    int row = p * 4 + (lane >> 4);
    int c16 = lane & 15;
    gload_lds16(Wh + ((size_t)row << 8) + ((c16 ^ (row & 7)) << 4), &wlds[p * 1024]);
  }
  stage_xt(0, 0);
  stage_xt(1, 1);

  float bw[3];
#pragma unroll
  for (int m = 0; m < 3; ++m) bw[m] = bb[h * 96 + rh * 48 + m * 16 + r16];
  float bq[2][4];
#pragma unroll
  for (int m = 0; m < 2; ++m)
#pragma unroll
    for (int r = 0; r < 4; ++r) bq[m][r] = bb[h * 96 + 64 + m * 16 + kg * 4 + r];

  f32x4 actx = {0.f, 0.f, 0.f, 0.f};   // quadrant (ckf=rh, cvf=pq), K = full 64 px
  float sk0 = 0.f, sk1 = 0.f;

  asm volatile("s_waitcnt vmcnt(4)" ::: "memory");   // W + tile0 done; tile1 in flight
  __builtin_amdgcn_sched_barrier(0);
  __builtin_amdgcn_s_barrier();
  __builtin_amdgcn_sched_barrier(0);

  const int base_w = (rh * 48 + r16) * 256;
  const int base_x = (pq * 32 + r16) * 256;

  // ---- W fragments -> registers, once (24 ds_read_b64 = 48 VGPR) ----
  ll wf[3][8];
#pragma unroll
  for (int m = 0; m < 3; ++m)
#pragma unroll
    for (int kk = 0; kk < 8; ++kk) {
      int sw = (((kk * 2 + (kg >> 1)) ^ (r16 & 7)) << 4) + ((kg & 1) << 3);
      wf[m][kk] = *(const ll*)&wlds[base_w + m * 4096 + sw];
    }

  for (int t = 0; t < NT; ++t) {
    int cur = t & 1, sb = t & 1, pb = sb ^ 1;
    // ---- ctx MFMA on previous tile's strips (bf16, one tile behind) ----
    if (t) {
#pragma unroll
      for (int ks = 0; ks < 2; ++ks) {
        int col = ks * 32 + kg * 8;
        short8 a = *(const short8*)&ekst[pb][rh * 16 + r16][col];
        short8 b = *(const short8*)&vst[pb][pq * 16 + r16][col];
        actx = __builtin_amdgcn_mfma_f32_16x16x32_bf16(a, b, actx, 0, 0, 0);
      }
    }
    // ---- K-loop: 48 rows x 32 px; only 2 x-frag b64 reads per kk ----
    f32x4 acc[3][2];
#pragma unroll
    for (int m = 0; m < 3; ++m) { acc[m][0] = (f32x4){0,0,0,0}; acc[m][1] = (f32x4){0,0,0,0}; }
    const unsigned char* xb = &xt[cur][0];
#pragma unroll
    for (int kk = 0; kk < 8; ++kk) {
      int sw = (((kk * 2 + (kg >> 1)) ^ (r16 & 7)) << 4) + ((kg & 1) << 3);
      ll xf0 = *(const ll*)&xb[base_x + sw];
      ll xf1 = *(const ll*)&xb[base_x + 4096 + sw];
      if (rh == 0) {
        acc[0][0] = __builtin_amdgcn_mfma_f32_16x16x32_fp8_fp8(xf0, wf[0][kk], acc[0][0], 0, 0, 0);
        acc[0][1] = __builtin_amdgcn_mfma_f32_16x16x32_fp8_fp8(xf1, wf[0][kk], acc[0][1], 0, 0, 0);
        acc[1][0] = __builtin_amdgcn_mfma_f32_16x16x32_fp8_fp8(xf0, wf[1][kk], acc[1][0], 0, 0, 0);
        acc[1][1] = __builtin_amdgcn_mfma_f32_16x16x32_fp8_fp8(xf1, wf[1][kk], acc[1][1], 0, 0, 0);
        acc[2][0] = __builtin_amdgcn_mfma_f32_16x16x32_fp8_fp8(xf0, wf[2][kk], acc[2][0], 0, 0, 0);
        acc[2][1] = __builtin_amdgcn_mfma_f32_16x16x32_fp8_fp8(xf1, wf[2][kk], acc[2][1], 0, 0, 0);
      } else {
        acc[0][0] = __builtin_amdgcn_mfma_f32_16x16x32_fp8_fp8(xf0, wf[0][kk], acc[0][0], 0, 0, 0);
        acc[0][1] = __builtin_amdgcn_mfma_f32_16x16x32_fp8_fp8(xf1, wf[0][kk], acc[0][1], 0, 0, 0);
        acc[1][0] = __builtin_amdgcn_mfma_f32_16x16x32_fp8_fp8(wf[1][kk], xf0, acc[1][0], 0, 0, 0);
        acc[1][1] = __builtin_amdgcn_mfma_f32_16x16x32_fp8_fp8(wf[1][kk], xf1, acc[1][1], 0, 0, 0);
        acc[2][0] = __builtin_amdgcn_mfma_f32_16x16x32_fp8_fp8(wf[2][kk], xf0, acc[2][0], 0, 0, 0);
        acc[2][1] = __builtin_amdgcn_mfma_f32_16x16x32_fp8_fp8(wf[2][kk], xf1, acc[2][1], 0, 0, 0);
      }
    }
    __builtin_amdgcn_s_barrier();          // barrier1: all waves done reading xt[cur]
    if (t + 2 < NT) stage_xt(cur, t + 2);  // refill freed buffer; full-tile DMA window

    // ---- epilogue (wave-local); acc * 1/64 undoes W pre-scale ----
    if (rh == 0) {
#pragma unroll
      for (int nf = 0; nf < 2; ++nf) {
        int col = pq * 32 + nf * 16 + kg * 4;
#pragma unroll
        for (int m = 0; m < 2; ++m) {       // k rows -> exp strips + S
          float e0 = __expf(acc[m][nf][0] * WSC + bw[m]);
          float e1 = __expf(acc[m][nf][1] * WSC + bw[m]);
          float e2 = __expf(acc[m][nf][2] * WSC + bw[m]);
          float e3 = __expf(acc[m][nf][3] * WSC + bw[m]);
          if (m == 0) sk0 += e0 + e1 + e2 + e3; else sk1 += e0 + e1 + e2 + e3;
          uint2 u = {cvt_pk_bf16(e0, e1), cvt_pk_bf16(e2, e3)};
          *(uint2*)&ekst[sb][m * 16 + r16][col] = u;
        }
        {                                    // v rows 0-15
          float v0 = acc[2][nf][0] * WSC + bw[2], v1 = acc[2][nf][1] * WSC + bw[2];
          float v2 = acc[2][nf][2] * WSC + bw[2], v3 = acc[2][nf][3] * WSC + bw[2];
          uint2 u = {cvt_pk_bf16(v0, v1), cvt_pk_bf16(v2, v3)};
          *(uint2*)&vst[sb][r16][col] = u;
        }
      }
    } else {
#pragma unroll
      for (int nf = 0; nf < 2; ++nf) {
        int col = pq * 32 + nf * 16 + kg * 4;
        {                                    // v rows 16-31
          float v0 = acc[0][nf][0] * WSC + bw[0], v1 = acc[0][nf][1] * WSC + bw[0];
          float v2 = acc[0][nf][2] * WSC + bw[0], v3 = acc[0][nf][3] * WSC + bw[0];
          uint2 u = {cvt_pk_bf16(v0, v1), cvt_pk_bf16(v2, v3)};
          *(uint2*)&vst[sb][16 + r16][col] = u;
        }
        // q: softmax over 32 ck, wholly in-wave (8 in-lane + shfl 16,32); store fp8
        float ea[4], eb[4];
        float s = 0.f;
#pragma unroll
        for (int r = 0; r < 4; ++r) {
          ea[r] = __expf(acc[1][nf][r] * WSC + bq[0][r]);
          eb[r] = __expf(acc[2][nf][r] * WSC + bq[1][r]);
          s += ea[r] + eb[r];
        }
        s += __shfl_xor(s, 16);
        s += __shfl_xor(s, 32);
        float inv = 1.f / s;
        int l = l0 + t * 64 + pq * 32 + nf * 16 + r16;
        unsigned char* qb = qbuf + (((size_t)nh * LSP + l) << 5);
        unsigned u0 = cvt4_fp8(ea[0] * inv, ea[1] * inv, ea[2] * inv, ea[3] * inv);
        unsigned u1 = cvt4_fp8(eb[0] * inv, eb[1] * inv, eb[2] * inv, eb[3] * inv);
        *(unsigned*)&qb[kg * 4]      = u0;
        *(unsigned*)&qb[16 + kg * 4] = u1;
      }
    }
    // barrier2: strips visible; next tile's buffer staged (counted, per-role)
    asm volatile("s_waitcnt lgkmcnt(0)" ::: "memory");
    __builtin_amdgcn_sched_barrier(0);
    if (t < NT - 2) {
      if (rh == 0) { asm volatile("s_waitcnt vmcnt(4)" ::: "memory"); }
      else         { asm volatile("s_waitcnt vmcnt(8)" ::: "memory"); }
    } else if (t == NT - 2) {
      if (rh == 0) { asm volatile("s_waitcnt vmcnt(0)" ::: "memory"); }
      else         { asm volatile("s_waitcnt vmcnt(4)" ::: "memory"); }
    }
    __builtin_amdgcn_sched_barrier(0);
    __builtin_amdgcn_s_barrier();
    __builtin_amdgcn_sched_barrier(0);
  }

  // final ctx on last tile's strips
#pragma unroll
  for (int ks = 0; ks < 2; ++ks) {
    int col = ks * 32 + kg * 8;
    short8 a = *(const short8*)&ekst[(NT - 1) & 1][rh * 16 + r16][col];
    short8 b = *(const short8*)&vst[(NT - 1) & 1][pq * 16 + r16][col];
    actx = __builtin_amdgcn_mfma_f32_16x16x32_bf16(a, b, actx, 0, 0, 0);
  }
  // flush: ctx quadrant + S rows
  float* cp = ctx + ((size_t)nh << 10);
#pragma unroll
  for (int r = 0; r < 4; ++r)
    atomicAdd(&cp[(rh * 16 + kg * 4 + r) * HC + pq * 16 + r16], actx[r]);
  if (rh == 0) {
    float s0 = sk0, s1 = sk1;
    s0 += __shfl_xor(s0, 16); s0 += __shfl_xor(s0, 32);
    s1 += __shfl_xor(s1, 16); s1 += __shfl_xor(s1, 32);
    if (kg == 0) {
      atomicAdd(&S[nh * HC + r16], s0);
      atomicAdd(&S[nh * HC + 16 + r16], s1);
    }
  }
}

// ---------------- kernel 2: att = (ctx/S)^T x q_soft + residual (norm folded in) ----------
__global__ __launch_bounds__(256)
void k_att(const float* __restrict__ x, const unsigned char* __restrict__ qbuf,
           const float* __restrict__ ctx, const float* __restrict__ S,
           float* __restrict__ out) {
  int b = blockIdx.x;
  int lc = b & 63;
  int nh = b >> 6;
  int h = nh & 7, n = nh >> 3;
  int tid = threadIdx.x, wid = tid >> 6, lane = tid & 63;
  int r16 = lane & 15, kg = lane >> 4;
  int lw = lc * 256 + wid * 64;

  // build fp8 A fragments from ctx/S (L2-hot; once per block)
  const float* cp = ctx + ((size_t)nh << 10);
  const float* Sp = S + nh * HC;
  float v0[8], v1[8];
#pragma unroll
  for (int j = 0; j < 8; ++j) {
    int ck = kg * 8 + j;
    float inv = 1.f / Sp[ck];
    v0[j] = cp[ck * HC + r16] * inv;        // A[cv=r16][ck]
    v1[j] = cp[ck * HC + 16 + r16] * inv;   // A[cv=16+r16][ck]
  }
  unsigned lo0 = cvt4_fp8(v0[0], v0[1], v0[2], v0[3]);
  unsigned hi0 = cvt4_fp8(v0[4], v0[5], v0[6], v0[7]);
  unsigned lo1 = cvt4_fp8(v1[0], v1[1], v1[2], v1[3]);
  unsigned hi1 = cvt4_fp8(v1[4], v1[5], v1[6], v1[7]);
  ll a0 = (ll)((unsigned long long)lo0 | ((unsigned long long)hi0 << 32));
  ll a1 = (ll)((unsigned long long)lo1 | ((unsigned long long)hi1 << 32));

  const unsigned char* qb = qbuf + (((size_t)nh * LSP) << 5);
  const float* xp = x   + ((size_t)n * CCH + (size_t)h * HC) * LSP;
  float*       op = out + ((size_t)n * CCH + (size_t)h * HC) * LSP;

#pragma unroll
  for (int t = 0; t < 4; ++t) {
    int l = lw + t * 16;
    ll bq = *(const ll*)&qb[((size_t)(l + r16) << 5) + kg * 8];  // softmaxed q [l][ck] fp8
    f32x4 d0 = {0, 0, 0, 0}, d1 = {0, 0, 0, 0};
    d0 = __builtin_amdgcn_mfma_f32_16x16x32_fp8_fp8(a0, bq, d0, 0, 0, 0);
    d1 = __builtin_amdgcn_mfma_f32_16x16x32_fp8_fp8(a1, bq, d1, 0, 0, 0);
#pragma unroll
    for (int r = 0; r < 4; ++r) {
      int cv = kg * 4 + r;
      int li = l + r16;
      op[(size_t)cv * LSP + li]        = d0[r] + xp[(size_t)cv * LSP + li];
      op[(size_t)(cv + 16) * LSP + li] = d1[r] + xp[(size_t)(cv + 16) * LSP + li];
    }
  }
}

extern "C" void kernel_launch(void* const* d_in, const int* in_sizes, int n_in,
                              void* d_out, int out_size, void* d_ws, size_t ws_size,
                              hipStream_t stream) {
  (void)in_sizes; (void)n_in; (void)out_size; (void)ws_size;
  const float* x  = (const float*)d_in[0];
  const float* Wk = (const float*)d_in[1];
  const float* bk = (const float*)d_in[2];
  const float* Wq = (const float*)d_in[3];
  const float* bq = (const float*)d_in[4];
  const float* Wv = (const float*)d_in[5];
  const float* bv = (const float*)d_in[6];
  float* out = (float*)d_out;

  char* ws = (char*)d_ws;
  unsigned char*  Wb   = (unsigned char*)(ws + 0);           //    196608 (fp8, x64-scaled)
  float*          bbp  = (float*)(ws + 196608);              //      3072
  float*          ctx  = (float*)(ws + 199680);              //    262144
  float*          S    = (float*)(ws + 494592);              //      8192
  unsigned char*  qbuf = (unsigned char*)(ws + 502784);      //  33554432 (fp8)
  unsigned char*  xT   = (unsigned char*)(ws + 34057216);    //  33554432 (fp8) -> 67611648

  k_pre<<<8960, 256, 0, stream>>>(x, xT, Wk, bk, Wq, bq, Wv, bv, Wb, bbp, ctx, S);
  k_fused<<<512, 256, 0, stream>>>(xT, Wb, bbp, qbuf, ctx, S);
  k_att<<<NB * NHEADS * 64, 256, 0, stream>>>(x, qbuf, ctx, S, out);
}

// Round 21
// 163.171 us; speedup vs baseline: 1.0983x; 1.0880x over previous
//
#include <hip/hip_runtime.h>

// EfficientAttention: N=8, C=256, H=W=128 (L=16384), HEADS=8, hc=32
// out = x + att,  att[n,h,cv,l] = sum_ck (ctx[ck,cv]/S[ck]) * softmax_ck(q)[ck,l]
// ctx[ck,cv] = sum_l exp(k[ck,l]) * v[cv,l],  S[ck] = sum_l exp(k[ck,l])
//
// R21 = best measured stage variants recombined:
//   k_pre   (R20): transpose + weight-prep merged (prep hides under HBM stream)
//   k_fused (R18): 2 blocks/CU, W frags in regs, fp8 staging, counted vmcnt
//   k_norm  (R16): ctx/S -> fp8 ctxT (separate tiny kernel)
//   k_att   (R16): fp8 ctxT + fp8 q, 2 b64 A-frag loads (R20's in-kernel norm
//                  fold was latency-bound: ~24 L2-cold scalar loads/block, -30us)

typedef __attribute__((ext_vector_type(8))) short short8;
typedef __attribute__((ext_vector_type(4))) float f32x4;
typedef long long ll;

#define NB     8
#define CCH    256
#define LSP    16384
#define NHEADS 8
#define HC     32
#define NT     32     // 64-px tiles per block (2048-px range)
#define WSC    0.015625f   // 1/64: undo W pre-scale

__device__ __forceinline__ unsigned cvt_pk_bf16(float lo, float hi) {
  unsigned r;
  asm("v_cvt_pk_bf16_f32 %0, %1, %2" : "=v"(r) : "v"(lo), "v"(hi));
  return r;
}
// 4 floats -> 4 fp8 e4m3 packed in a u32 (HW cvt, RNE)
__device__ __forceinline__ unsigned cvt4_fp8(float a, float b, float c, float d) {
  unsigned r;
  asm("v_cvt_pk_fp8_f32 %0, %1, %2\n\t"
      "v_cvt_pk_fp8_f32 %0, %3, %4 op_sel:[0,0,1]"
      : "=v"(r) : "v"(a), "v"(b), "v"(c), "v"(d));
  return r;
}
// float -> fp8 e4m3fn (software, for once-only prep path)
__device__ __forceinline__ unsigned char f2fp8(float f) {
  union { float f; unsigned u; } v; v.f = f;
  unsigned s = (v.u >> 24) & 0x80u;
  unsigned x = v.u & 0x7FFFFFFFu;
  if (x < 0x3C800000u) {
    float a = fabsf(f);
    int q = (int)rintf(a * 512.f);
    return (unsigned char)(s | (unsigned)q);
  }
  unsigned r = x + 0xFFFFFu + ((x >> 20) & 1u);
  unsigned e = r >> 23;
  unsigned m = (r >> 20) & 7u;
  int fe = (int)e - 120;
  if (fe > 15 || (fe == 15 && m == 7)) return (unsigned char)(s | 0x7Eu);
  return (unsigned char)(s | ((unsigned)fe << 3) | m);
}
__device__ __forceinline__ void gload_lds16(const unsigned char* g, unsigned char* l) {
  __builtin_amdgcn_global_load_lds(
      (const __attribute__((address_space(1))) unsigned int*)g,
      (__attribute__((address_space(3))) unsigned int*)l, 16, 0, 0);
}

// ---------------- kernel 0: transpose (blocks 0..8191) + prep (blocks 8192..8959) --------
__global__ __launch_bounds__(256)
void k_pre(const float* __restrict__ x, unsigned char* __restrict__ xT,
           const float* __restrict__ Wk, const float* __restrict__ bk,
           const float* __restrict__ Wq, const float* __restrict__ bq,
           const float* __restrict__ Wv, const float* __restrict__ bv,
           unsigned char* __restrict__ Wb, float* __restrict__ bb,
           float* __restrict__ ctx, float* __restrict__ S) {
  __shared__ float tile[64][65];
  int b = blockIdx.x;
  if (b < 8192) {
    int ct = b & 3;
    int lt = (b >> 2) & 255;
    int n  = b >> 10;
    int c0 = ct * 64, l0 = lt * 64;
    int t = threadIdx.x;
    int li = t & 63, cr = t >> 6;
    const float* xp = x + (size_t)n * CCH * LSP;
#pragma unroll
    for (int i = 0; i < 16; ++i) {
      int ci = cr * 16 + i;
      tile[ci][li] = xp[(size_t)(c0 + ci) * LSP + l0 + li];
    }
    __syncthreads();
    int cq = t & 15, lg = t >> 4;
    unsigned char* xo = xT + ((size_t)n * LSP + l0) * CCH + c0;
#pragma unroll
    for (int i = 0; i < 4; ++i) {
      int l = lg * 4 + i;
      unsigned pk = cvt4_fp8(tile[cq * 4][l], tile[cq * 4 + 1][l],
                             tile[cq * 4 + 2][l], tile[cq * 4 + 3][l]);
      *(unsigned*)&xo[(size_t)l * CCH + cq * 4] = pk;
    }
  } else {
    int idx = (b - 8192) * 256 + threadIdx.x;
    if (idx < NHEADS * 96 * CCH) {
      int c = idx & (CCH - 1);
      int row = (idx >> 8) % 96;
      int h = idx / (96 * CCH);
      int ch = h * HC;
      float val;
      if (row < HC)          val = Wk[(ch + row) * CCH + c];
      else if (row < 2 * HC) val = Wv[(ch + row - HC) * CCH + c];
      else                   val = Wq[(ch + row - 2 * HC) * CCH + c];
      Wb[idx] = f2fp8(val * 64.f);
    }
    if (idx < NHEADS * 96) {
      int row = idx % 96, h = idx / 96, ch = h * HC;
      float val;
      if (row < HC)          val = bk[ch + row];
      else if (row < 2 * HC) val = bv[ch + row - HC];
      else                   val = bq[ch + row - 2 * HC];
      bb[idx] = val;
    }
    if (idx < NB * NHEADS * HC * HC) ctx[idx] = 0.f;
    if (idx < NB * NHEADS * HC)      S[idx]   = 0.f;
  }
}

// ---------------- kernel 1: fused QKV, 2 blocks/CU, W frags in registers (R18) ------------
// grid 512 = 8h x 8n x 8g; bid = h*64 + n*8 + g -> h-siblings differ by 64 (mult of 8)
// -> same XCD (x L2-shared). 4 waves = rh{0,1} x pq{0,1}; wave tile 48 rows x 32 px.
// W frags loaded to regs once from LDS (24 b64 = 48 VGPR) -> K-loop reads 2 x-frags/kk.
__global__ __launch_bounds__(256)
void k_fused(const unsigned char* __restrict__ xT,
             const unsigned char* __restrict__ Wb, const float* __restrict__ bb,
             unsigned char* __restrict__ qbuf, float* __restrict__ ctx,
             float* __restrict__ S) {
  __shared__ unsigned char wlds[96 * 256];        // 24 KiB (staged once)
  __shared__ unsigned char xt[2][64 * 256];       // 32 KiB dbuf
  __shared__ unsigned short ekst[2][32][72];      // 9 KiB exp(k) strips, dbuf
  __shared__ unsigned short vst[2][32][72];       // 9 KiB v strips, dbuf

  int bid = (int)blockIdx.x;
  int h = bid >> 6;
  int r6 = bid & 63;
  int n = r6 >> 3, g = r6 & 7;
  int l0 = g << 11;                  // 2048-px range
  int nh = n * NHEADS + h;
  int tid = threadIdx.x;
  int wid = tid >> 6, lane = tid & 63;
  int r16 = lane & 15, kg = lane >> 4;
  int rh = wid >> 1;          // row half (48 rows)
  int pq = wid & 1;           // px half (32 px)

  const unsigned char* xTn = xT + ((size_t)n << 14) * CCH;
  const unsigned char* Wh = Wb + (size_t)h * 96 * CCH;

  // stage 64px x 256ch fp8 tile: 16 x 1KiB pieces, 4/wave; dest linear,
  // source 16B-chunk XOR (3-bit involution, rule 21)
  auto stage_xt = [&](int buf, int tt) {
    int lb = l0 + tt * 64;
#pragma unroll
    for (int i = 0; i < 4; ++i) {
      int p = wid * 4 + i;                   // 0..15
      int px = p * 4 + (lane >> 4);
      int c16 = lane & 15;
      gload_lds16(xTn + ((size_t)(lb + px) << 8) + ((c16 ^ (px & 7)) << 4),
                  &xt[buf][p * 1024]);
    }
  };

  // prologue: W (24 pieces, 6/wave) + tiles 0,1
#pragma unroll
  for (int i = 0; i < 6; ++i) {
    int p = wid * 6 + i;
    int row = p * 4 + (lane >> 4);
    int c16 = lane & 15;
    gload_lds16(Wh + ((size_t)row << 8) + ((c16 ^ (row & 7)) << 4), &wlds[p * 1024]);
  }
  stage_xt(0, 0);
  stage_xt(1, 1);

  float bw[3];
#pragma unroll
  for (int m = 0; m < 3; ++m) bw[m] = bb[h * 96 + rh * 48 + m * 16 + r16];
  float bq[2][4];
#pragma unroll
  for (int m = 0; m < 2; ++m)
#pragma unroll
    for (int r = 0; r < 4; ++r) bq[m][r] = bb[h * 96 + 64 + m * 16 + kg * 4 + r];

  f32x4 actx = {0.f, 0.f, 0.f, 0.f};   // quadrant (ckf=rh, cvf=pq), K = full 64 px
  float sk0 = 0.f, sk1 = 0.f;

  asm volatile("s_waitcnt vmcnt(4)" ::: "memory");   // W + tile0 done; tile1 in flight
  __builtin_amdgcn_sched_barrier(0);
  __builtin_amdgcn_s_barrier();
  __builtin_amdgcn_sched_barrier(0);

  const int base_w = (rh * 48 + r16) * 256;
  const int base_x = (pq * 32 + r16) * 256;

  // ---- W fragments -> registers, once (24 ds_read_b64 = 48 VGPR) ----
  ll wf[3][8];
#pragma unroll
  for (int m = 0; m < 3; ++m)
#pragma unroll
    for (int kk = 0; kk < 8; ++kk) {
      int sw = (((kk * 2 + (kg >> 1)) ^ (r16 & 7)) << 4) + ((kg & 1) << 3);
      wf[m][kk] = *(const ll*)&wlds[base_w + m * 4096 + sw];
    }

  for (int t = 0; t < NT; ++t) {
    int cur = t & 1, sb = t & 1, pb = sb ^ 1;
    // ---- ctx MFMA on previous tile's strips (bf16, one tile behind) ----
    if (t) {
#pragma unroll
      for (int ks = 0; ks < 2; ++ks) {
        int col = ks * 32 + kg * 8;
        short8 a = *(const short8*)&ekst[pb][rh * 16 + r16][col];
        short8 b = *(const short8*)&vst[pb][pq * 16 + r16][col];
        actx = __builtin_amdgcn_mfma_f32_16x16x32_bf16(a, b, actx, 0, 0, 0);
      }
    }
    // ---- K-loop: 48 rows x 32 px; only 2 x-frag b64 reads per kk ----
    f32x4 acc[3][2];
#pragma unroll
    for (int m = 0; m < 3; ++m) { acc[m][0] = (f32x4){0,0,0,0}; acc[m][1] = (f32x4){0,0,0,0}; }
    const unsigned char* xb = &xt[cur][0];
#pragma unroll
    for (int kk = 0; kk < 8; ++kk) {
      int sw = (((kk * 2 + (kg >> 1)) ^ (r16 & 7)) << 4) + ((kg & 1) << 3);
      ll xf0 = *(const ll*)&xb[base_x + sw];
      ll xf1 = *(const ll*)&xb[base_x + 4096 + sw];
      if (rh == 0) {
        acc[0][0] = __builtin_amdgcn_mfma_f32_16x16x32_fp8_fp8(xf0, wf[0][kk], acc[0][0], 0, 0, 0);
        acc[0][1] = __builtin_amdgcn_mfma_f32_16x16x32_fp8_fp8(xf1, wf[0][kk], acc[0][1], 0, 0, 0);
        acc[1][0] = __builtin_amdgcn_mfma_f32_16x16x32_fp8_fp8(xf0, wf[1][kk], acc[1][0], 0, 0, 0);
        acc[1][1] = __builtin_amdgcn_mfma_f32_16x16x32_fp8_fp8(xf1, wf[1][kk], acc[1][1], 0, 0, 0);
        acc[2][0] = __builtin_amdgcn_mfma_f32_16x16x32_fp8_fp8(xf0, wf[2][kk], acc[2][0], 0, 0, 0);
        acc[2][1] = __builtin_amdgcn_mfma_f32_16x16x32_fp8_fp8(xf1, wf[2][kk], acc[2][1], 0, 0, 0);
      } else {
        acc[0][0] = __builtin_amdgcn_mfma_f32_16x16x32_fp8_fp8(xf0, wf[0][kk], acc[0][0], 0, 0, 0);
        acc[0][1] = __builtin_amdgcn_mfma_f32_16x16x32_fp8_fp8(xf1, wf[0][kk], acc[0][1], 0, 0, 0);
        acc[1][0] = __builtin_amdgcn_mfma_f32_16x16x32_fp8_fp8(wf[1][kk], xf0, acc[1][0], 0, 0, 0);
        acc[1][1] = __builtin_amdgcn_mfma_f32_16x16x32_fp8_fp8(wf[1][kk], xf1, acc[1][1], 0, 0, 0);
        acc[2][0] = __builtin_amdgcn_mfma_f32_16x16x32_fp8_fp8(wf[2][kk], xf0, acc[2][0], 0, 0, 0);
        acc[2][1] = __builtin_amdgcn_mfma_f32_16x16x32_fp8_fp8(wf[2][kk], xf1, acc[2][1], 0, 0, 0);
      }
    }
    __builtin_amdgcn_s_barrier();          // barrier1: all waves done reading xt[cur]
    if (t + 2 < NT) stage_xt(cur, t + 2);  // refill freed buffer; full-tile DMA window

    // ---- epilogue (wave-local); acc * 1/64 undoes W pre-scale ----
    if (rh == 0) {
#pragma unroll
      for (int nf = 0; nf < 2; ++nf) {
        int col = pq * 32 + nf * 16 + kg * 4;
#pragma unroll
        for (int m = 0; m < 2; ++m) {       // k rows -> exp strips + S
          float e0 = __expf(acc[m][nf][0] * WSC + bw[m]);
          float e1 = __expf(acc[m][nf][1] * WSC + bw[m]);
          float e2 = __expf(acc[m][nf][2] * WSC + bw[m]);
          float e3 = __expf(acc[m][nf][3] * WSC + bw[m]);
          if (m == 0) sk0 += e0 + e1 + e2 + e3; else sk1 += e0 + e1 + e2 + e3;
          uint2 u = {cvt_pk_bf16(e0, e1), cvt_pk_bf16(e2, e3)};
          *(uint2*)&ekst[sb][m * 16 + r16][col] = u;
        }
        {                                    // v rows 0-15
          float v0 = acc[2][nf][0] * WSC + bw[2], v1 = acc[2][nf][1] * WSC + bw[2];
          float v2 = acc[2][nf][2] * WSC + bw[2], v3 = acc[2][nf][3] * WSC + bw[2];
          uint2 u = {cvt_pk_bf16(v0, v1), cvt_pk_bf16(v2, v3)};
          *(uint2*)&vst[sb][r16][col] = u;
        }
      }
    } else {
#pragma unroll
      for (int nf = 0; nf < 2; ++nf) {
        int col = pq * 32 + nf * 16 + kg * 4;
        {                                    // v rows 16-31
          float v0 = acc[0][nf][0] * WSC + bw[0], v1 = acc[0][nf][1] * WSC + bw[0];
          float v2 = acc[0][nf][2] * WSC + bw[0], v3 = acc[0][nf][3] * WSC + bw[0];
          uint2 u = {cvt_pk_bf16(v0, v1), cvt_pk_bf16(v2, v3)};
          *(uint2*)&vst[sb][16 + r16][col] = u;
        }
        // q: softmax over 32 ck, wholly in-wave (8 in-lane + shfl 16,32); store fp8
        float ea[4], eb[4];
        float s = 0.f;
#pragma unroll
        for (int r = 0; r < 4; ++r) {
          ea[r] = __expf(acc[1][nf][r] * WSC + bq[0][r]);
          eb[r] = __expf(acc[2][nf][r] * WSC + bq[1][r]);
          s += ea[r] + eb[r];
        }
        s += __shfl_xor(s, 16);
        s += __shfl_xor(s, 32);
        float inv = 1.f / s;
        int l = l0 + t * 64 + pq * 32 + nf * 16 + r16;
        unsigned char* qb = qbuf + (((size_t)nh * LSP + l) << 5);
        unsigned u0 = cvt4_fp8(ea[0] * inv, ea[1] * inv, ea[2] * inv, ea[3] * inv);
        unsigned u1 = cvt4_fp8(eb[0] * inv, eb[1] * inv, eb[2] * inv, eb[3] * inv);
        *(unsigned*)&qb[kg * 4]      = u0;
        *(unsigned*)&qb[16 + kg * 4] = u1;
      }
    }
    // barrier2: strips visible; next tile's buffer staged (counted, per-role)
    asm volatile("s_waitcnt lgkmcnt(0)" ::: "memory");
    __builtin_amdgcn_sched_barrier(0);
    if (t < NT - 2) {
      if (rh == 0) { asm volatile("s_waitcnt vmcnt(4)" ::: "memory"); }
      else         { asm volatile("s_waitcnt vmcnt(8)" ::: "memory"); }
    } else if (t == NT - 2) {
      if (rh == 0) { asm volatile("s_waitcnt vmcnt(0)" ::: "memory"); }
      else         { asm volatile("s_waitcnt vmcnt(4)" ::: "memory"); }
    }
    __builtin_amdgcn_sched_barrier(0);
    __builtin_amdgcn_s_barrier();
    __builtin_amdgcn_sched_barrier(0);
  }

  // final ctx on last tile's strips
#pragma unroll
  for (int ks = 0; ks < 2; ++ks) {
    int col = ks * 32 + kg * 8;
    short8 a = *(const short8*)&ekst[(NT - 1) & 1][rh * 16 + r16][col];
    short8 b = *(const short8*)&vst[(NT - 1) & 1][pq * 16 + r16][col];
    actx = __builtin_amdgcn_mfma_f32_16x16x32_bf16(a, b, actx, 0, 0, 0);
  }
  // flush: ctx quadrant + S rows
  float* cp = ctx + ((size_t)nh << 10);
#pragma unroll
  for (int r = 0; r < 4; ++r)
    atomicAdd(&cp[(rh * 16 + kg * 4 + r) * HC + pq * 16 + r16], actx[r]);
  if (rh == 0) {
    float s0 = sk0, s1 = sk1;
    s0 += __shfl_xor(s0, 16); s0 += __shfl_xor(s0, 32);
    s1 += __shfl_xor(s1, 16); s1 += __shfl_xor(s1, 32);
    if (kg == 0) {
      atomicAdd(&S[nh * HC + r16], s0);
      atomicAdd(&S[nh * HC + 16 + r16], s1);
    }
  }
}

// ---------------- kernel 2: ctx/S, transpose, -> fp8 ----------------
__global__ void k_norm(const float* __restrict__ ctx, const float* __restrict__ S,
                       unsigned char* __restrict__ ctxT) {
  int idx = blockIdx.x * 256 + threadIdx.x;  // 65536 = [n][h][ck][cv]
  int cv = idx & 31, ck = (idx >> 5) & 31, nh = idx >> 10;
  float v = ctx[idx] / S[(nh << 5) + ck];
  ctxT[(nh << 10) + (cv << 5) + ck] = f2fp8(v);
}

// ---------------- kernel 3: att = ctxT (fp8) x q_soft (fp8) + residual ----------------
__global__ __launch_bounds__(256)
void k_att(const float* __restrict__ x, const unsigned char* __restrict__ qbuf,
           const unsigned char* __restrict__ ctxT, float* __restrict__ out) {
  int b = blockIdx.x;
  int lc = b & 63;
  int nh = b >> 6;
  int h = nh & 7, n = nh >> 3;
  int tid = threadIdx.x, wid = tid >> 6, lane = tid & 63;
  int r16 = lane & 15, kg = lane >> 4;
  int lw = lc * 256 + wid * 64;

  const unsigned char* cp = ctxT + ((size_t)nh << 10);
  ll a0 = *(const ll*)&cp[(r16 << 5) + kg * 8];          // A[cv][ck], cv 0-15
  ll a1 = *(const ll*)&cp[((16 + r16) << 5) + kg * 8];   // cv 16-31
  const unsigned char* qb = qbuf + (((size_t)nh * LSP) << 5);
  const float* xp = x   + ((size_t)n * CCH + (size_t)h * HC) * LSP;
  float*       op = out + ((size_t)n * CCH + (size_t)h * HC) * LSP;

#pragma unroll
  for (int t = 0; t < 4; ++t) {
    int l = lw + t * 16;
    ll bq = *(const ll*)&qb[((size_t)(l + r16) << 5) + kg * 8];  // softmaxed q [l][ck] fp8
    f32x4 d0 = {0, 0, 0, 0}, d1 = {0, 0, 0, 0};
    d0 = __builtin_amdgcn_mfma_f32_16x16x32_fp8_fp8(a0, bq, d0, 0, 0, 0);
    d1 = __builtin_amdgcn_mfma_f32_16x16x32_fp8_fp8(a1, bq, d1, 0, 0, 0);
#pragma unroll
    for (int r = 0; r < 4; ++r) {
      int cv = kg * 4 + r;
      int li = l + r16;
      op[(size_t)cv * LSP + li]        = d0[r] + xp[(size_t)cv * LSP + li];
      op[(size_t)(cv + 16) * LSP + li] = d1[r] + xp[(size_t)(cv + 16) * LSP + li];
    }
  }
}

extern "C" void kernel_launch(void* const* d_in, const int* in_sizes, int n_in,
                              void* d_out, int out_size, void* d_ws, size_t ws_size,
                              hipStream_t stream) {
  (void)in_sizes; (void)n_in; (void)out_size; (void)ws_size;
  const float* x  = (const float*)d_in[0];
  const float* Wk = (const float*)d_in[1];
  const float* bk = (const float*)d_in[2];
  const float* Wq = (const float*)d_in[3];
  const float* bq = (const float*)d_in[4];
  const float* Wv = (const float*)d_in[5];
  const float* bv = (const float*)d_in[6];
  float* out = (float*)d_out;

  char* ws = (char*)d_ws;
  unsigned char*  Wb   = (unsigned char*)(ws + 0);           //    196608 (fp8, x64-scaled)
  float*          bbp  = (float*)(ws + 196608);              //      3072
  float*          ctx  = (float*)(ws + 199680);              //    262144
  unsigned char*  ctxT = (unsigned char*)(ws + 461824);      //     32768 (fp8)
  float*          S    = (float*)(ws + 494592);              //      8192
  unsigned char*  qbuf = (unsigned char*)(ws + 502784);      //  33554432 (fp8)
  unsigned char*  xT   = (unsigned char*)(ws + 34057216);    //  33554432 (fp8) -> 67611648

  k_pre<<<8960, 256, 0, stream>>>(x, xT, Wk, bk, Wq, bq, Wv, bv, Wb, bbp, ctx, S);
  k_fused<<<512, 256, 0, stream>>>(xT, Wb, bbp, qbuf, ctx, S);
  k_norm<<<256, 256, 0, stream>>>(ctx, S, ctxT);
  k_att<<<NB * NHEADS * 64, 256, 0, stream>>>(x, qbuf, ctxT, out);
}